// Round 4
// baseline (82.160 us; speedup 1.0000x reference)
//
#include <hip/hip_runtime.h>
#include <math.h>

#define CH 40
#define IMW 1024
#define XS 48                 // halves per x1 position (padded from 40; 40..47 never read)
#define W2T_HALVES (48*48*8)  // [kchunk 0..47][co 0..47][j 0..7]
#define Z1_OFF W2T_HALVES     // z1[40] halves right after w2t

typedef _Float16 v8h __attribute__((ext_vector_type(8)));
typedef _Float16 v2h __attribute__((ext_vector_type(2)));
typedef float    v4f __attribute__((ext_vector_type(4)));
typedef float    v2f __attribute__((ext_vector_type(2)));

// gelu(tanh approx) == x * sigmoid(2*0.79788456*(x+0.044715x^3))
__device__ __forceinline__ float gelu_fast(float x) {
    float u = 1.5957691216057308f * (x + 0.044715f * x * x * x);
    return x * __builtin_amdgcn_rcpf(1.0f + __expf(-u));
}

// ---------------- pre-kernel: build f16 weight table + z1 in ws ----------------
__global__ __launch_bounds__(256) void prep_kernel(
    const float* __restrict__ w2,
    const float* __restrict__ b1, const float* __restrict__ s1,
    const float* __restrict__ bb1,
    _Float16* __restrict__ ws)
{
    int idx0 = blockIdx.x * 256 + threadIdx.x;
    for (int idx = idx0; idx < W2T_HALVES; idx += gridDim.x * 256) {
        int j   = idx & 7;
        int co  = (idx >> 3) % 48;
        int kgg = idx / (48 * 8);
        int k   = kgg * 8 + j;          // k = window*40 + ci
        float v = 0.0f;
        if (co < CH && k < 360) {
            int wi = k / 40, ci = k - wi * 40;
            v = w2[(wi * CH + ci) * CH + co];
        }
        ws[idx] = (_Float16)v;
    }
    if (blockIdx.x == 0 && threadIdx.x < CH) {
        int t = threadIdx.x;
        float mu = 0.f, m2 = 0.f;
        for (int i = 0; i < CH; i++) mu += b1[i];
        mu /= CH;
        for (int i = 0; i < CH; i++) { float d = b1[i] - mu; m2 += d * d; }
        float rs = rsqrtf(m2 / CH + 1e-6f);
        float y = (b1[t] - mu) * rs * s1[t] + bb1[t];
        ws[Z1_OFF + t] = (_Float16)gelu_fast(y);
    }
}

// ---------------- main kernel: one token per block ----------------
__global__ __launch_bounds__(256) void sgn_kernel(
    const float* __restrict__ img,
    const float* __restrict__ w1, const float* __restrict__ b1,
    const float* __restrict__ s1, const float* __restrict__ bb1,
    const float* __restrict__ b2g,
    const float* __restrict__ s2, const float* __restrict__ bb2,
    const float* __restrict__ dw, const float* __restrict__ db,
    const _Float16* __restrict__ ws,
    float* __restrict__ out)
{
    // Phase B/C: x1h f16 [17*17*XS] = 27744 B.  Phase C/D: partials f32[4][64][48] = 49152 B.
    __shared__ __align__(16) unsigned char sbuf[49152];
    _Float16* x1h = (_Float16*)sbuf;
    float*    part = (float*)sbuf;
    __shared__ float img_s[16][16];
    __shared__ unsigned koff_s[48];
    __shared__ float red[4][6];

    const int f   = blockIdx.x;
    const int cfg = f >> 10;
    const int ij  = f & 1023;
    const int ti  = ij >> 5, tj = ij & 31;
    const int sx  = cfg & 1, sy = cfg >> 1;
    const int cr  = 2 * ti + sx, cc = 2 * tj + sy;

    const int t = threadIdx.x;

    // ---- Phase A: stage image cell + koff LUT ----
    {
        int r = t >> 4, c = t & 15;
        img_s[r][c] = img[(cr * 16 + r) * IMW + cc * 16 + c];
    }
    if (t < 48) {
        int s = t >> 2, kg = t & 3;
        int k0 = 32 * s + 8 * kg;
        unsigned v;
        if (k0 >= 360) v = 0x80000000u;
        else {
            int wi = k0 / 40, ci0 = k0 - wi * 40;
            int dr = wi / 3, dc = wi - 3 * dr;
            v = (unsigned)((dr * 17 + dc) * XS + ci0);
        }
        koff_s[t] = v;
    }
    __syncthreads();

    // ---- Phase B: conv1 + LN1 + gelu -> x1h (f16); 4 threads/pos, 10 ch each ----
    {
        const int pos = t >> 2, sub = t & 3;
        const int r = pos >> 3, c = pos & 7;
        float vin[9];
        #pragma unroll
        for (int dr = 0; dr < 3; dr++)
            #pragma unroll
            for (int dc = 0; dc < 3; dc++) {
                int rr = 2 * r + dr, ccc = 2 * c + dc;
                vin[dr * 3 + dc] = (rr < 16 && ccc < 16) ? img_s[rr][ccc] : 0.0f;
            }
        const int ch0 = sub * 10;
        float y[10];
        float s_own = 0.f;
        #pragma unroll
        for (int u = 0; u < 10; u++) {
            int ch = ch0 + u;
            float a = b1[ch];
            #pragma unroll
            for (int k = 0; k < 9; k++) a += vin[k] * w1[k * CH + ch];
            y[u] = a; s_own += a;
        }
        s_own += __shfl_xor(s_own, 1, 64);
        s_own += __shfl_xor(s_own, 2, 64);
        float mu = s_own * (1.0f / CH);
        float v_own = 0.f;
        #pragma unroll
        for (int u = 0; u < 10; u++) { float d = y[u] - mu; v_own += d * d; }
        v_own += __shfl_xor(v_own, 1, 64);
        v_own += __shfl_xor(v_own, 2, 64);
        float rs = rsqrtf(v_own * (1.0f / CH) + 1e-6f);
        const int base = (r * 17 + c) * XS + ch0;   // halves, byte addr 4-aligned
        #pragma unroll
        for (int u2 = 0; u2 < 5; u2++) {
            v2h hv;
            int ch_a = ch0 + 2 * u2, ch_b = ch_a + 1;
            hv[0] = (_Float16)gelu_fast((y[2*u2]   - mu) * rs * s1[ch_a] + bb1[ch_a]);
            hv[1] = (_Float16)gelu_fast((y[2*u2+1] - mu) * rs * s1[ch_b] + bb1[ch_b]);
            *(v2h*)&x1h[base + 2 * u2] = hv;
        }
    }
    // border/constant fill: 225 non-real positions across 256 threads (2 rounds)
    {
        const v8h* zsrc = (const v8h*)&ws[Z1_OFF];
        v8h z0 = zsrc[0], z1v = zsrc[1], z2 = zsrc[2], z3 = zsrc[3], z4 = zsrc[4];
        v8h zz = (v8h)0;
        #pragma unroll
        for (int round = 0; round < 2; round++) {
            int pp = t + round * 256;
            if (pp >= 289) continue;
            int r = pp / 17, c = pp - r * 17;
            if (r < 8 && c < 8) continue;
            bool zero = (r == 16) || (c == 16);
            int base = pp * XS;
            *(v8h*)&x1h[base]      = zero ? zz : z0;
            *(v8h*)&x1h[base + 8]  = zero ? zz : z1v;
            *(v8h*)&x1h[base + 16] = zero ? zz : z2;
            *(v8h*)&x1h[base + 24] = zero ? zz : z3;
            *(v8h*)&x1h[base + 32] = zero ? zz : z4;
        }
    }
    __syncthreads();

    // ---- Phase C: conv2 MFMA GEMM, K-split across waves ----
    // wave w: full M=64, N=48, K in [96w, 96w+96)  -> 4 Mtiles x 3 Ntiles x 3 Ksteps
    v4f acc[4][3];
    {
        const int wv   = t >> 6;
        const int lane = t & 63;
        const int row  = lane & 15;
        const int kg   = lane >> 4;
        unsigned pbase[4];
        #pragma unroll
        for (int m = 0; m < 4; m++) {
            int o = (m << 4) | row;
            int p = o >> 3, q = o & 7;
            pbase[m] = (unsigned)((34 * p + 2 * q) * XS);
        }
        #pragma unroll
        for (int m = 0; m < 4; m++)
            #pragma unroll
            for (int n = 0; n < 3; n++) acc[m][n] = (v4f){0,0,0,0};

        const v8h* wtab = (const v8h*)ws;
        #pragma unroll
        for (int s = 0; s < 3; s++) {
            int kc = wv * 12 + (s << 2) + kg;
            unsigned koff = koff_s[kc];
            const v8h* wb = wtab + kc * 48;
            v8h bf0 = wb[row];
            v8h bf1 = wb[16 + row];
            v8h bf2 = wb[32 + row];
            #pragma unroll
            for (int m = 0; m < 4; m++) {
                unsigned aoff = (koff & 0x80000000u) ? 0u : (pbase[m] + koff);
                v8h a = *(const v8h*)&x1h[aoff];
                acc[m][0] = __builtin_amdgcn_mfma_f32_16x16x32_f16(a, bf0, acc[m][0], 0, 0, 0);
                acc[m][1] = __builtin_amdgcn_mfma_f32_16x16x32_f16(a, bf1, acc[m][1], 0, 0, 0);
                acc[m][2] = __builtin_amdgcn_mfma_f32_16x16x32_f16(a, bf2, acc[m][2], 0, 0, 0);
            }
        }
    }
    __syncthreads();   // all x1h reads complete; safe to overwrite with partials

    {
        const int wv   = t >> 6;
        const int lane = t & 63;
        const int co_b = lane & 15;
        const int kg   = lane >> 4;
        float* pw = &part[wv * 3072];
        #pragma unroll
        for (int m = 0; m < 4; m++)
            #pragma unroll
            for (int j = 0; j < 4; j++) {
                int pos = (m << 4) | (kg << 2) | j;
                float* pp = pw + pos * 48;
                pp[co_b]      = acc[m][0][j];
                pp[16 + co_b] = acc[m][1][j];
                pp[32 + co_b] = acc[m][2][j];
            }
    }
    __syncthreads();

    // ---- Phase D: reduce partials + bias + LN2 + gelu + dense; 4 threads/pos, 10 ch ----
    {
        const int pos = t >> 2, sub = t & 3;
        const int co0 = sub * 10;
        float vv[10];
        #pragma unroll
        for (int w = 0; w < 4; w++) {
            const float* pp = &part[w * 3072 + pos * 48 + co0];
            #pragma unroll
            for (int u2 = 0; u2 < 5; u2++) {
                v2f x = *(const v2f*)&pp[u2 * 2];
                if (w == 0) { vv[2*u2] = x[0]; vv[2*u2+1] = x[1]; }
                else        { vv[2*u2] += x[0]; vv[2*u2+1] += x[1]; }
            }
        }
        float s_own = 0.f;
        #pragma unroll
        for (int u = 0; u < 10; u++) { vv[u] += b2g[co0 + u]; s_own += vv[u]; }
        s_own += __shfl_xor(s_own, 1, 64);
        s_own += __shfl_xor(s_own, 2, 64);
        float mu = s_own * (1.0f / CH);
        float v_own = 0.f;
        #pragma unroll
        for (int u = 0; u < 10; u++) { float d = vv[u] - mu; v_own += d * d; }
        v_own += __shfl_xor(v_own, 1, 64);
        v_own += __shfl_xor(v_own, 2, 64);
        float rs = rsqrtf(v_own * (1.0f / CH) + 1e-6f);

        float acc6[6] = {0.f, 0.f, 0.f, 0.f, 0.f, 0.f};
        const float* wp = &dw[(pos * CH + co0) * 6];
        #pragma unroll
        for (int u = 0; u < 10; u++) {
            float gv = gelu_fast((vv[u] - mu) * rs * s2[co0 + u] + bb2[co0 + u]);
            v2f w01 = *(const v2f*)&wp[u * 6];
            v2f w23 = *(const v2f*)&wp[u * 6 + 2];
            v2f w45 = *(const v2f*)&wp[u * 6 + 4];
            acc6[0] += gv * w01[0]; acc6[1] += gv * w01[1];
            acc6[2] += gv * w23[0]; acc6[3] += gv * w23[1];
            acc6[4] += gv * w45[0]; acc6[5] += gv * w45[1];
        }
        #pragma unroll
        for (int off = 32; off > 0; off >>= 1)
            #pragma unroll
            for (int k = 0; k < 6; k++) acc6[k] += __shfl_down(acc6[k], off, 64);
        int wv = t >> 6, lane = t & 63;
        if (lane == 0) {
            #pragma unroll
            for (int k = 0; k < 6; k++) red[wv][k] = acc6[k];
        }
        __syncthreads();
        if (t == 0) {
            #pragma unroll
            for (int k = 0; k < 6; k++)
                out[f * 6 + k] = red[0][k] + red[1][k] + red[2][k] + red[3][k] + db[k];
        }
    }
}

extern "C" void kernel_launch(void* const* d_in, const int* in_sizes, int n_in,
                              void* d_out, int out_size, void* d_ws, size_t ws_size,
                              hipStream_t stream) {
    const float* img = (const float*)d_in[0];
    // d_in[1] = masks: analytically redundant (mask == cell id), not read.
    const float* w1  = (const float*)d_in[2];
    const float* b1  = (const float*)d_in[3];
    const float* s1  = (const float*)d_in[4];
    const float* bb1 = (const float*)d_in[5];
    const float* w2  = (const float*)d_in[6];
    const float* b2  = (const float*)d_in[7];
    const float* s2  = (const float*)d_in[8];
    const float* bb2 = (const float*)d_in[9];
    const float* dw  = (const float*)d_in[10];
    const float* db  = (const float*)d_in[11];
    float* out = (float*)d_out;
    _Float16* ws = (_Float16*)d_ws;

    prep_kernel<<<32, 256, 0, stream>>>(w2, b1, s1, bb1, ws);
    sgn_kernel<<<4096, 256, 0, stream>>>(img, w1, b1, s1, bb1,
                                         b2, s2, bb2, dw, db, ws, out);
}

// Round 6
// 54.107 us; speedup vs baseline: 1.5185x; 1.5185x over previous
//
#include <hip/hip_runtime.h>
#include <math.h>

#define CH 40
#define IMW 1024
#define XS 48                 // halves per x1 position (padded from 40; 40..47 never read)
#define W2T_HALVES (48*48*8)  // [kchunk 0..47][co 0..47][j 0..7]
#define Z1_OFF W2T_HALVES     // z1[40] halves right after w2t
#define Y2S 50                // f32 stride of y2 transpose buffer

typedef _Float16 v8h __attribute__((ext_vector_type(8)));
typedef _Float16 v2h __attribute__((ext_vector_type(2)));
typedef float    v4f __attribute__((ext_vector_type(4)));
typedef float    v2f __attribute__((ext_vector_type(2)));

// gelu(tanh approx) == x * sigmoid(2*0.79788456*(x+0.044715x^3))
__device__ __forceinline__ float gelu_fast(float x) {
    float u = 1.5957691216057308f * (x + 0.044715f * x * x * x);
    return x * __builtin_amdgcn_rcpf(1.0f + __expf(-u));
}

// ---------------- pre-kernel: build f16 weight table + z1 in ws ----------------
__global__ __launch_bounds__(256) void prep_kernel(
    const float* __restrict__ w2,
    const float* __restrict__ b1, const float* __restrict__ s1,
    const float* __restrict__ bb1,
    _Float16* __restrict__ ws)
{
    int idx0 = blockIdx.x * 256 + threadIdx.x;
    for (int idx = idx0; idx < W2T_HALVES; idx += gridDim.x * 256) {
        int j   = idx & 7;
        int co  = (idx >> 3) % 48;
        int kgg = idx / (48 * 8);
        int k   = kgg * 8 + j;          // k = window*40 + ci
        float v = 0.0f;
        if (co < CH && k < 360) {
            int wi = k / 40, ci = k - wi * 40;
            v = w2[(wi * CH + ci) * CH + co];
        }
        ws[idx] = (_Float16)v;
    }
    if (blockIdx.x == 0 && threadIdx.x < CH) {
        int t = threadIdx.x;
        float mu = 0.f, m2 = 0.f;
        for (int i = 0; i < CH; i++) mu += b1[i];
        mu /= CH;
        for (int i = 0; i < CH; i++) { float d = b1[i] - mu; m2 += d * d; }
        float rs = rsqrtf(m2 / CH + 1e-6f);
        float y = (b1[t] - mu) * rs * s1[t] + bb1[t];
        ws[Z1_OFF + t] = (_Float16)gelu_fast(y);
    }
}

// ---------------- main kernel: one token per block ----------------
__global__ __launch_bounds__(256) void sgn_kernel(
    const float* __restrict__ img,
    const float* __restrict__ w1, const float* __restrict__ b1,
    const float* __restrict__ s1, const float* __restrict__ bb1,
    const float* __restrict__ b2g,
    const float* __restrict__ s2, const float* __restrict__ bb2,
    const float* __restrict__ dw, const float* __restrict__ db,
    const _Float16* __restrict__ ws,
    float* __restrict__ out)
{
    // x1h f16 [17*17*XS] = 27744 B; after conv2 reads, overlaid by y2 f32 [64][Y2S] = 12800 B
    __shared__ __align__(16) unsigned char sbuf[17 * 17 * XS * 2];
    _Float16* x1h = (_Float16*)sbuf;
    float*    y2  = (float*)sbuf;
    __shared__ float img_s[16][16];
    __shared__ float w1t[40 * 12];     // conv1 weights transposed [ch][k], k padded to 12
    __shared__ float p1s[120];         // b1 | s1 | bb1
    __shared__ float p2s[120];         // b2 | s2 | bb2
    __shared__ unsigned koff_s[48];
    __shared__ float red[4][6];

    const int f   = blockIdx.x;
    const int cfg = f >> 10;
    const int ij  = f & 1023;
    const int ti  = ij >> 5, tj = ij & 31;
    const int sx  = cfg & 1, sy = cfg >> 1;
    const int cr  = 2 * ti + sx, cc = 2 * tj + sy;

    const int t = threadIdx.x;

    // ---- Phase A: stage image cell, params, w1 transpose, koff LUT ----
    {
        int r = t >> 4, c = t & 15;
        img_s[r][c] = img[(cr * 16 + r) * IMW + cc * 16 + c];
    }
    for (int i = t; i < 360; i += 256) {
        int k = i / 40, ch = i - k * 40;
        w1t[ch * 12 + k] = w1[i];
    }
    if (t < 120) {
        p1s[t] = (t < 40) ? b1[t] : (t < 80 ? s1[t - 40] : bb1[t - 80]);
    } else if (t >= 128 && t < 248) {
        int i = t - 128;
        p2s[i] = (i < 40) ? b2g[i] : (i < 80 ? s2[i - 40] : bb2[i - 80]);
    }
    if (t < 48) {
        int s = t >> 2, kg = t & 3;
        int k0 = 32 * s + 8 * kg;
        unsigned v;
        if (k0 >= 360) v = 0x80000000u;
        else {
            int wi = k0 / 40, ci0 = k0 - wi * 40;
            int dr = wi / 3, dc = wi - 3 * dr;
            v = (unsigned)((dr * 17 + dc) * XS + ci0);
        }
        koff_s[t] = v;
    }
    __syncthreads();

    // ---- Phase B: conv1 + LN1 + gelu -> x1h (f16); 4 threads/pos, 10 ch each ----
    {
        const int pos = t >> 2, sub = t & 3;
        const int r = pos >> 3, c = pos & 7;
        float vin[9];
        #pragma unroll
        for (int dr = 0; dr < 3; dr++)
            #pragma unroll
            for (int dc = 0; dc < 3; dc++) {
                int rr = 2 * r + dr, ccc = 2 * c + dc;
                vin[dr * 3 + dc] = (rr < 16 && ccc < 16) ? img_s[rr][ccc] : 0.0f;
            }
        const int ch0 = sub * 10;
        float y[10];
        float s_own = 0.f;
        #pragma unroll
        for (int u = 0; u < 10; u++) {
            float a = p1s[ch0 + u];
            const float* wr = &w1t[(ch0 + u) * 12];
            #pragma unroll
            for (int k = 0; k < 9; k++) a += vin[k] * wr[k];
            y[u] = a; s_own += a;
        }
        s_own += __shfl_xor(s_own, 1, 64);
        s_own += __shfl_xor(s_own, 2, 64);
        float mu = s_own * (1.0f / CH);
        float v_own = 0.f;
        #pragma unroll
        for (int u = 0; u < 10; u++) { float d = y[u] - mu; v_own += d * d; }
        v_own += __shfl_xor(v_own, 1, 64);
        v_own += __shfl_xor(v_own, 2, 64);
        float rs = rsqrtf(v_own * (1.0f / CH) + 1e-6f);
        const int base = (r * 17 + c) * XS + ch0;   // halves, byte addr 4-aligned
        #pragma unroll
        for (int u2 = 0; u2 < 5; u2++) {
            v2h hv;
            int ch_a = ch0 + 2 * u2, ch_b = ch_a + 1;
            hv[0] = (_Float16)gelu_fast((y[2*u2]   - mu) * rs * p1s[40 + ch_a] + p1s[80 + ch_a]);
            hv[1] = (_Float16)gelu_fast((y[2*u2+1] - mu) * rs * p1s[40 + ch_b] + p1s[80 + ch_b]);
            *(v2h*)&x1h[base + 2 * u2] = hv;
        }
    }
    // border/constant fill: 225 non-real positions across 256 threads (2 rounds)
    {
        const v8h* zsrc = (const v8h*)&ws[Z1_OFF];
        v8h z0 = zsrc[0], z1v = zsrc[1], z2 = zsrc[2], z3 = zsrc[3], z4 = zsrc[4];
        v8h zz = (v8h)0;
        #pragma unroll
        for (int round = 0; round < 2; round++) {
            int pp = t + round * 256;
            if (pp >= 289) continue;
            int r = pp / 17, c = pp - r * 17;
            if (r < 8 && c < 8) continue;
            bool zero = (r == 16) || (c == 16);
            int base = pp * XS;
            *(v8h*)&x1h[base]      = zero ? zz : z0;
            *(v8h*)&x1h[base + 8]  = zero ? zz : z1v;
            *(v8h*)&x1h[base + 16] = zero ? zz : z2;
            *(v8h*)&x1h[base + 24] = zero ? zz : z3;
            *(v8h*)&x1h[base + 32] = zero ? zz : z4;
        }
    }
    __syncthreads();

    // ---- Phase C: conv2 MFMA GEMM; wave wv owns M-tile wv (16 pos), full K, N=48 ----
    v4f acc0 = {0,0,0,0}, acc1 = {0,0,0,0}, acc2 = {0,0,0,0};
    {
        const int wv   = t >> 6;
        const int lane = t & 63;
        const int row  = lane & 15;
        const int kg   = lane >> 4;
        const int o    = (wv << 4) | row;
        const int p = o >> 3, q = o & 7;
        const unsigned pbase = (unsigned)((34 * p + 2 * q) * XS);

        const v8h* wtab = (const v8h*)ws;
        #pragma unroll
        for (int s = 0; s < 12; s++) {
            unsigned koff = koff_s[(s << 2) | kg];
            unsigned aoff = (koff & 0x80000000u) ? 0u : (pbase + koff);
            v8h a = *(const v8h*)&x1h[aoff];
            const v8h* wb = wtab + ((s * 4 + kg) * 48);
            v8h bf0 = wb[row];
            v8h bf1 = wb[16 + row];
            v8h bf2 = wb[32 + row];
            acc0 = __builtin_amdgcn_mfma_f32_16x16x32_f16(a, bf0, acc0, 0, 0, 0);
            acc1 = __builtin_amdgcn_mfma_f32_16x16x32_f16(a, bf1, acc1, 0, 0, 0);
            acc2 = __builtin_amdgcn_mfma_f32_16x16x32_f16(a, bf2, acc2, 0, 0, 0);
        }
    }
    __syncthreads();   // all x1h reads complete; safe to overwrite with y2

    // ---- transpose raw conv2 output to y2 [64][Y2S] ----
    {
        const int wv   = t >> 6;
        const int lane = t & 63;
        const int co_b = lane & 15;
        const int kg   = lane >> 4;
        #pragma unroll
        for (int j = 0; j < 4; j++) {
            int pos = (wv << 4) | (kg << 2) | j;
            y2[pos * Y2S + co_b]      = acc0[j];
            y2[pos * Y2S + 16 + co_b] = acc1[j];
            if (co_b < 8)
                y2[pos * Y2S + 32 + co_b] = acc2[j];
        }
    }
    __syncthreads();

    // ---- Phase D: bias + LN2 + gelu + dense; 4 threads/pos, 10 ch each ----
    {
        const int pos = t >> 2, sub = t & 3;
        const int co0 = sub * 10;
        float vv[10];
        float s_own = 0.f;
        #pragma unroll
        for (int u2 = 0; u2 < 5; u2++) {
            v2f x = *(const v2f*)&y2[pos * Y2S + co0 + 2 * u2];
            float a = x[0] + p2s[co0 + 2 * u2];
            float b = x[1] + p2s[co0 + 2 * u2 + 1];
            vv[2*u2] = a; vv[2*u2+1] = b;
            s_own += a + b;
        }
        s_own += __shfl_xor(s_own, 1, 64);
        s_own += __shfl_xor(s_own, 2, 64);
        float mu = s_own * (1.0f / CH);
        float v_own = 0.f;
        #pragma unroll
        for (int u = 0; u < 10; u++) { float d = vv[u] - mu; v_own += d * d; }
        v_own += __shfl_xor(v_own, 1, 64);
        v_own += __shfl_xor(v_own, 2, 64);
        float rs = rsqrtf(v_own * (1.0f / CH) + 1e-6f);

        float acc6[6] = {0.f, 0.f, 0.f, 0.f, 0.f, 0.f};
        const float* wp = &dw[(pos * CH + co0) * 6];
        #pragma unroll
        for (int u = 0; u < 10; u++) {
            float gv = gelu_fast((vv[u] - mu) * rs * p2s[40 + co0 + u] + p2s[80 + co0 + u]);
            v2f w01 = *(const v2f*)&wp[u * 6];
            v2f w23 = *(const v2f*)&wp[u * 6 + 2];
            v2f w45 = *(const v2f*)&wp[u * 6 + 4];
            acc6[0] += gv * w01[0]; acc6[1] += gv * w01[1];
            acc6[2] += gv * w23[0]; acc6[3] += gv * w23[1];
            acc6[4] += gv * w45[0]; acc6[5] += gv * w45[1];
        }
        #pragma unroll
        for (int off = 32; off > 0; off >>= 1)
            #pragma unroll
            for (int k = 0; k < 6; k++) acc6[k] += __shfl_down(acc6[k], off, 64);
        int wv = t >> 6, lane = t & 63;
        if (lane == 0) {
            #pragma unroll
            for (int k = 0; k < 6; k++) red[wv][k] = acc6[k];
        }
        __syncthreads();
        if (t == 0) {
            #pragma unroll
            for (int k = 0; k < 6; k++)
                out[f * 6 + k] = red[0][k] + red[1][k] + red[2][k] + red[3][k] + db[k];
        }
    }
}

extern "C" void kernel_launch(void* const* d_in, const int* in_sizes, int n_in,
                              void* d_out, int out_size, void* d_ws, size_t ws_size,
                              hipStream_t stream) {
    const float* img = (const float*)d_in[0];
    // d_in[1] = masks: analytically redundant (mask == cell id), not read.
    const float* w1  = (const float*)d_in[2];
    const float* b1  = (const float*)d_in[3];
    const float* s1  = (const float*)d_in[4];
    const float* bb1 = (const float*)d_in[5];
    const float* w2  = (const float*)d_in[6];
    const float* b2  = (const float*)d_in[7];
    const float* s2  = (const float*)d_in[8];
    const float* bb2 = (const float*)d_in[9];
    const float* dw  = (const float*)d_in[10];
    const float* db  = (const float*)d_in[11];
    float* out = (float*)d_out;
    _Float16* ws = (_Float16*)d_ws;

    prep_kernel<<<32, 256, 0, stream>>>(w2, b1, s1, bb1, ws);
    sgn_kernel<<<4096, 256, 0, stream>>>(img, w1, b1, s1, bb1,
                                         b2, s2, bb2, dw, db, ws, out);
}